// Round 1
// baseline (8642.996 us; speedup 1.0000x reference)
//
#include <hip/hip_runtime.h>
#include <hip/hip_bf16.h>
#include <math.h>

#define BATCH 16384
#define HDIM  512
#define VOCAB 32
#define STEPS 20
#define G4    (4 * HDIM)   // 2048

// ---------------------------------------------------------------------------
// init kernels
// ---------------------------------------------------------------------------
__global__ void init_xb_kernel(const float* __restrict__ W_ih,
                               const float* __restrict__ b_ih,
                               const float* __restrict__ b_hh,
                               const float* __restrict__ x0,
                               float* __restrict__ xb) {
    int n = blockIdx.x * blockDim.x + threadIdx.x;
    if (n >= G4) return;
    float s = b_ih[n] + b_hh[n];
    const float* wr = W_ih + (size_t)n * VOCAB;
    #pragma unroll
    for (int v = 0; v < VOCAB; v++) s += wr[v] * x0[v];
    xb[n] = s;
}

__global__ void init_mask_kernel(float* __restrict__ mask) {
    int b = blockIdx.x * blockDim.x + threadIdx.x;
    if (b < BATCH) mask[b] = 1.0f;
}

// ---------------------------------------------------------------------------
// Fused SGEMM (gates = h @ W_hh^T + xb) + LSTM cell update.
// Tile: 128 batch rows x (32 j x 4 gates). BK = 16. 256 threads, 8x8/thread.
// Tile column index n_local = jj*4 + gate  (gate fastest) so every thread
// owns complete (i,f,g,o) quadruples -> cell update fused in epilogue.
// ---------------------------------------------------------------------------
__global__ __launch_bounds__(256)
void gemm_cell_kernel(const float* __restrict__ h_in,
                      float* __restrict__ c,
                      float* __restrict__ h_out,
                      const float* __restrict__ W_hh,
                      const float* __restrict__ xb) {
    __shared__ __align__(16) float As[16][132];  // [k][m], padded stride
    __shared__ __align__(16) float Ws[16][132];  // [k][n_local]

    const int tid = threadIdx.x;
    const int m0  = blockIdx.x * 128;
    const int j0  = blockIdx.y * 32;
    const int tm  = tid >> 4;   // 0..15
    const int tn  = tid & 15;   // 0..15

    float acc[8][8];
    #pragma unroll
    for (int i = 0; i < 8; i++)
        #pragma unroll
        for (int j = 0; j < 8; j++) acc[i][j] = 0.0f;

    const int lrow = tid >> 2;        // 0..63
    const int lk   = (tid & 3) * 4;   // 0,4,8,12
    const int jj_a = lrow >> 2;       // 0..15
    const int g_a  = lrow & 3;        // 0..3

    const float* Arow0 = h_in + (size_t)(m0 + lrow) * HDIM;
    const float* Arow1 = h_in + (size_t)(m0 + lrow + 64) * HDIM;
    const float* Wrow0 = W_hh + (size_t)(g_a * HDIM + j0 + jj_a) * HDIM;
    const float* Wrow1 = W_hh + (size_t)(g_a * HDIM + j0 + jj_a + 16) * HDIM;

    for (int k0 = 0; k0 < HDIM; k0 += 16) {
        float4 a0 = *(const float4*)(Arow0 + k0 + lk);
        float4 a1 = *(const float4*)(Arow1 + k0 + lk);
        float4 w0 = *(const float4*)(Wrow0 + k0 + lk);
        float4 w1 = *(const float4*)(Wrow1 + k0 + lk);
        __syncthreads();  // protect previous iteration's reads
        As[lk + 0][lrow]      = a0.x; As[lk + 1][lrow]      = a0.y;
        As[lk + 2][lrow]      = a0.z; As[lk + 3][lrow]      = a0.w;
        As[lk + 0][lrow + 64] = a1.x; As[lk + 1][lrow + 64] = a1.y;
        As[lk + 2][lrow + 64] = a1.z; As[lk + 3][lrow + 64] = a1.w;
        Ws[lk + 0][lrow]      = w0.x; Ws[lk + 1][lrow]      = w0.y;
        Ws[lk + 2][lrow]      = w0.z; Ws[lk + 3][lrow]      = w0.w;
        Ws[lk + 0][lrow + 64] = w1.x; Ws[lk + 1][lrow + 64] = w1.y;
        Ws[lk + 2][lrow + 64] = w1.z; Ws[lk + 3][lrow + 64] = w1.w;
        __syncthreads();
        #pragma unroll
        for (int k = 0; k < 16; k++) {
            float4 av0 = *(const float4*)&As[k][tm * 4];
            float4 av1 = *(const float4*)&As[k][64 + tm * 4];
            float4 wv0 = *(const float4*)&Ws[k][tn * 4];
            float4 wv1 = *(const float4*)&Ws[k][64 + tn * 4];
            float a[8] = {av0.x, av0.y, av0.z, av0.w, av1.x, av1.y, av1.z, av1.w};
            float w[8] = {wv0.x, wv0.y, wv0.z, wv0.w, wv1.x, wv1.y, wv1.z, wv1.w};
            #pragma unroll
            for (int i = 0; i < 8; i++)
                #pragma unroll
                for (int j = 0; j < 8; j++)
                    acc[i][j] = fmaf(a[i], w[j], acc[i][j]);
        }
    }

    // epilogue: LSTM cell update. acc[mi][jsel*4 + g] is the gate quad for
    // b = m0 + (mi<4 ? tm*4+mi : 64+tm*4+mi-4), j = j0 + tn + jsel*16.
    #pragma unroll
    for (int mi = 0; mi < 8; mi++) {
        int b = m0 + ((mi < 4) ? (tm * 4 + mi) : (64 + tm * 4 + mi - 4));
        #pragma unroll
        for (int jsel = 0; jsel < 2; jsel++) {
            int j = j0 + tn + jsel * 16;
            float gi = acc[mi][jsel * 4 + 0] + xb[0 * HDIM + j];
            float gf = acc[mi][jsel * 4 + 1] + xb[1 * HDIM + j];
            float gg = acc[mi][jsel * 4 + 2] + xb[2 * HDIM + j];
            float go = acc[mi][jsel * 4 + 3] + xb[3 * HDIM + j];
            float si = 1.0f / (1.0f + expf(-gi));
            float sf = 1.0f / (1.0f + expf(-gf));
            float tg = tanhf(gg);
            float so = 1.0f / (1.0f + expf(-go));
            size_t idx = (size_t)b * HDIM + j;
            float cn = sf * c[idx] + si * tg;
            c[idx] = cn;
            h_out[idx] = so * tanhf(cn);
        }
    }
}

// ---------------------------------------------------------------------------
// Per-step output: logits = h @ W_out^T + b_out (V=32), softmax/argmax,
// one-hot message, mask bookkeeping, per-block log-prob partial.
// Block = 256 threads = 8 batch rows x 32 lanes(vocab).
// ---------------------------------------------------------------------------
__global__ __launch_bounds__(256)
void out_step_kernel(const float* __restrict__ h,
                     const float* __restrict__ W_out,
                     const float* __restrict__ b_out,
                     float* __restrict__ mask,
                     float* __restrict__ msg_t,
                     float* __restrict__ maskout_t,
                     float* __restrict__ lp_part,
                     const int* __restrict__ eos_ptr) {
    __shared__ __align__(16) float hs[8][128];
    __shared__ float ws[128][32];
    __shared__ float red[8];

    const int tid = threadIdx.x;
    const int v   = tid & 31;
    const int bb  = tid >> 5;          // 0..7
    const int b0  = blockIdx.x * 8;
    const int eos = *eos_ptr;

    float logit = 0.0f;
    for (int k0 = 0; k0 < HDIM; k0 += 128) {
        __syncthreads();
        // stage h: 8 rows x 128 k, coalesced float4
        *(float4*)&hs[bb][v * 4] =
            *(const float4*)(h + (size_t)(b0 + bb) * HDIM + k0 + v * 4);
        // stage W_out transposed: thread (v) loads 16 consecutive k of row v
        {
            int kk = bb * 16;
            const float* src = W_out + (size_t)v * HDIM + k0 + kk;
            float4 q0 = *(const float4*)(src + 0);
            float4 q1 = *(const float4*)(src + 4);
            float4 q2 = *(const float4*)(src + 8);
            float4 q3 = *(const float4*)(src + 12);
            ws[kk + 0][v] = q0.x;  ws[kk + 1][v] = q0.y;
            ws[kk + 2][v] = q0.z;  ws[kk + 3][v] = q0.w;
            ws[kk + 4][v] = q1.x;  ws[kk + 5][v] = q1.y;
            ws[kk + 6][v] = q1.z;  ws[kk + 7][v] = q1.w;
            ws[kk + 8][v] = q2.x;  ws[kk + 9][v] = q2.y;
            ws[kk + 10][v] = q2.z; ws[kk + 11][v] = q2.w;
            ws[kk + 12][v] = q3.x; ws[kk + 13][v] = q3.y;
            ws[kk + 14][v] = q3.z; ws[kk + 15][v] = q3.w;
        }
        __syncthreads();
        #pragma unroll
        for (int k = 0; k < 128; k++)
            logit = fmaf(hs[bb][k], ws[k][v], logit);
    }
    logit += b_out[v];

    // argmax (first index on ties, matching np.argmax) within 32 lanes
    float mval = logit;
    int   midx = v;
    #pragma unroll
    for (int off = 16; off > 0; off >>= 1) {
        float ov = __shfl_xor(mval, off, 32);
        int   oi = __shfl_xor(midx, off, 32);
        if (ov > mval || (ov == mval && oi < midx)) { mval = ov; midx = oi; }
    }
    // stable logsumexp
    float ex = expf(logit - mval);
    float s  = ex;
    #pragma unroll
    for (int off = 16; off > 0; off >>= 1) s += __shfl_xor(s, off, 32);

    const int b = b0 + bb;
    msg_t[(size_t)b * VOCAB + v] = (v == midx) ? 1.0f : 0.0f;
    if (v == 0) {
        float mo = mask[b];
        maskout_t[b] = mo;
        // log(prob of argmax) = -log(sum exp(logit - max))
        red[bb] = mo * (-logf(s));
        if (midx == eos) mask[b] = 0.0f;
    }
    __syncthreads();
    if (tid == 0) {
        float t = 0.0f;
        #pragma unroll
        for (int i = 0; i < 8; i++) t += red[i];
        lp_part[blockIdx.x] = t;
    }
}

__global__ void reduce_lp_kernel(const float* __restrict__ parts, int n,
                                 float* __restrict__ out) {
    __shared__ float sm[256];
    float s = 0.0f;
    for (int i = threadIdx.x; i < n; i += 256) s += parts[i];
    sm[threadIdx.x] = s;
    __syncthreads();
    for (int off = 128; off > 0; off >>= 1) {
        if (threadIdx.x < off) sm[threadIdx.x] += sm[threadIdx.x + off];
        __syncthreads();
    }
    if (threadIdx.x == 0) *out = sm[0];
}

// ---------------------------------------------------------------------------
extern "C" void kernel_launch(void* const* d_in, const int* in_sizes, int n_in,
                              void* d_out, int out_size, void* d_ws, size_t ws_size,
                              hipStream_t stream) {
    const float* enc_h  = (const float*)d_in[0];
    const float* enc_c  = (const float*)d_in[1];
    const float* W_ih   = (const float*)d_in[2];
    const float* b_ih   = (const float*)d_in[3];
    const float* W_hh   = (const float*)d_in[4];
    const float* b_hh   = (const float*)d_in[5];
    const float* W_out  = (const float*)d_in[6];
    const float* b_out  = (const float*)d_in[7];
    const float* x0     = (const float*)d_in[8];
    const int*   eosP   = (const int*)d_in[9];

    float* out = (float*)d_out;
    float* msg     = out;                                        // [20,16384,32]
    float* maskout = out + (size_t)STEPS * BATCH * VOCAB;        // [20,1,16384]
    float* lp_out  = maskout + (size_t)STEPS * BATCH;            // scalar

    // workspace layout (floats)
    const size_t NH = (size_t)BATCH * HDIM;       // 8388608
    float* h0       = (float*)d_ws;
    float* h1       = h0 + NH;
    float* cbuf     = h1 + NH;
    float* maskbuf  = cbuf + NH;                  // 16384
    float* xb       = maskbuf + BATCH;            // 2048
    float* lp_parts = xb + G4;                    // 20*2048 = 40960

    // init state (d_ws is re-poisoned before every call)
    hipMemcpyAsync(h0, enc_h, NH * sizeof(float), hipMemcpyDeviceToDevice, stream);
    hipMemcpyAsync(cbuf, enc_c, NH * sizeof(float), hipMemcpyDeviceToDevice, stream);
    init_mask_kernel<<<(BATCH + 255) / 256, 256, 0, stream>>>(maskbuf);
    init_xb_kernel<<<(G4 + 255) / 256, 256, 0, stream>>>(W_ih, b_ih, b_hh, x0, xb);

    for (int t = 0; t < STEPS; t++) {
        const float* hin = (t & 1) ? h1 : h0;
        float* hout      = (t & 1) ? h0 : h1;
        gemm_cell_kernel<<<dim3(BATCH / 128, HDIM / 32), 256, 0, stream>>>(
            hin, cbuf, hout, W_hh, xb);
        out_step_kernel<<<BATCH / 8, 256, 0, stream>>>(
            hout, W_out, b_out, maskbuf,
            msg + (size_t)t * BATCH * VOCAB,
            maskout + (size_t)t * BATCH,
            lp_parts + (size_t)t * (BATCH / 8),
            eosP);
    }
    reduce_lp_kernel<<<1, 256, 0, stream>>>(lp_parts, STEPS * (BATCH / 8), lp_out);
}

// Round 2
// 3513.355 us; speedup vs baseline: 2.4600x; 2.4600x over previous
//
#include <hip/hip_runtime.h>
#include <hip/hip_bf16.h>
#include <math.h>

#define BATCH 16384
#define HDIM  512
#define VOCAB 32
#define STEPS 20
#define G4    (4 * HDIM)   // 2048

typedef _Float16 f16;
typedef _Float16 f16x8 __attribute__((ext_vector_type(8)));
typedef _Float16 f16x4 __attribute__((ext_vector_type(4)));
typedef float    f32x4 __attribute__((ext_vector_type(4)));

#define SH   256.0f            // h pre-scale before fp16 split
#define SW   1024.0f           // W pre-scale before fp16 split
#define SINV (1.0f / (SH * SW))
#define HINV (1.0f / SH)

// ---------------------------------------------------------------------------
// async global->LDS (16B per lane); LDS dst is wave-uniform base + lane*16
// ---------------------------------------------------------------------------
__device__ __forceinline__ void gload16(const void* g, void* l) {
#if defined(__has_builtin) && __has_builtin(__builtin_amdgcn_global_load_lds)
    __builtin_amdgcn_global_load_lds(
        (const __attribute__((address_space(1))) void*)g,
        (__attribute__((address_space(3))) void*)l, 16, 0, 0);
#else
    *(float4*)l = *(const float4*)g;
#endif
}

// ---------------------------------------------------------------------------
// init kernels
// ---------------------------------------------------------------------------
__global__ void init_xb_kernel(const float* __restrict__ W_ih,
                               const float* __restrict__ b_ih,
                               const float* __restrict__ b_hh,
                               const float* __restrict__ x0,
                               float* __restrict__ xb) {
    int n = blockIdx.x * blockDim.x + threadIdx.x;
    if (n >= G4) return;
    float s = b_ih[n] + b_hh[n];
    const float* wr = W_ih + (size_t)n * VOCAB;
    #pragma unroll
    for (int v = 0; v < VOCAB; v++) s += wr[v] * x0[v];
    xb[n] = s;
}

__global__ void init_mask_kernel(float* __restrict__ mask) {
    int b = blockIdx.x * blockDim.x + threadIdx.x;
    if (b < BATCH) mask[b] = 1.0f;
}

// split scaled fp32 -> (hi, lo) fp16 pair
__global__ void split_kernel(const float* __restrict__ src, float scale,
                             f16* __restrict__ hi, f16* __restrict__ lo,
                             int n) {
    int i = blockIdx.x * blockDim.x + threadIdx.x;
    if (i >= n) return;
    float x = src[i] * scale;
    f16 h = (f16)x;
    f16 l = (f16)(x - (float)h);
    hi[i] = h;
    lo[i] = l;
}

// ---------------------------------------------------------------------------
// MFMA GEMM (gates = h @ W_hh^T, 3-pass fp16 split) + fused LSTM cell.
// Block tile: 128 m x 128 n_local, n_local = gate*32 + jj (gate-major).
// 4 waves: (wm, wn) = (wave>>1, wave&1); wave tile 64m x (4 gates x 16 jj).
// mfma_f32_16x16x32_f16 layouts (m89/m91/m120-verified family):
//   A: lane holds A[m = lane&15][k = (lane>>4)*8 + j]
//   B: lane holds B[k = (lane>>4)*8 + j][n = lane&15]
//   D: lane holds D[row = (lane>>4)*4 + reg][col = lane&15]
// ---------------------------------------------------------------------------
__global__ __launch_bounds__(256)
void gemm_cell_mfma(const f16* __restrict__ hhi, const f16* __restrict__ hlo,
                    f16* __restrict__ hhi_o,  f16* __restrict__ hlo_o,
                    float* __restrict__ c,
                    const f16* __restrict__ Wh, const f16* __restrict__ Wl,
                    const float* __restrict__ xb) {
    __shared__ f16 Ah[128 * 32];
    __shared__ f16 Al[128 * 32];
    __shared__ f16 Bh[128 * 32];
    __shared__ f16 Bl[128 * 32];

    const int tid  = threadIdx.x;
    const int lane = tid & 63;
    const int wave = tid >> 6;
    const int wm   = wave >> 1;       // m half (0/1)
    const int wn   = wave & 1;        // jj half (0/1)
    const int m0   = blockIdx.x * 128;
    const int j0   = blockIdx.y * 32;

    f32x4 acc[4][4];                  // [mt][gate]
    #pragma unroll
    for (int a = 0; a < 4; a++)
        #pragma unroll
        for (int b = 0; b < 4; b++)
            acc[a][b] = (f32x4){0.f, 0.f, 0.f, 0.f};

    // staging geometry: thread t covers LDS rows r0 and r0+64, 16B granule cc
    const int r0 = tid >> 2;            // 0..63
    const int cc = (tid & 3) * 8;       // f16 offset of 16B granule
    const int wr0 = ((r0) >> 5) * HDIM + j0 + (r0 & 31);           // W row, LDS row r0
    const int wr1 = ((r0 + 64) >> 5) * HDIM + j0 + ((r0 + 64) & 31); // LDS row r0+64

    const int quad = lane >> 4;
    const int l15  = lane & 15;

    for (int k0 = 0; k0 < HDIM; k0 += 32) {
        __syncthreads();   // previous tile's frag reads done before overwrite
        gload16(hhi + (size_t)(m0 + r0) * HDIM + k0 + cc,      &Ah[r0 * 32 + cc]);
        gload16(hhi + (size_t)(m0 + r0 + 64) * HDIM + k0 + cc, &Ah[(r0 + 64) * 32 + cc]);
        gload16(hlo + (size_t)(m0 + r0) * HDIM + k0 + cc,      &Al[r0 * 32 + cc]);
        gload16(hlo + (size_t)(m0 + r0 + 64) * HDIM + k0 + cc, &Al[(r0 + 64) * 32 + cc]);
        gload16(Wh + (size_t)wr0 * HDIM + k0 + cc,             &Bh[r0 * 32 + cc]);
        gload16(Wh + (size_t)wr1 * HDIM + k0 + cc,             &Bh[(r0 + 64) * 32 + cc]);
        gload16(Wl + (size_t)wr0 * HDIM + k0 + cc,             &Bl[r0 * 32 + cc]);
        gload16(Wl + (size_t)wr1 * HDIM + k0 + cc,             &Bl[(r0 + 64) * 32 + cc]);
        __syncthreads();   // drains vmcnt -> LDS tile ready

        f16x8 bh[4], bl[4];
        #pragma unroll
        for (int g = 0; g < 4; g++) {
            int r = g * 32 + wn * 16 + l15;     // n_local row
            bh[g] = *(const f16x8*)&Bh[r * 32 + quad * 8];
            bl[g] = *(const f16x8*)&Bl[r * 32 + quad * 8];
        }
        #pragma unroll
        for (int mt = 0; mt < 4; mt++) {
            int mr = wm * 64 + mt * 16 + l15;
            f16x8 ah = *(const f16x8*)&Ah[mr * 32 + quad * 8];
            f16x8 al = *(const f16x8*)&Al[mr * 32 + quad * 8];
            #pragma unroll
            for (int g = 0; g < 4; g++) {
                acc[mt][g] = __builtin_amdgcn_mfma_f32_16x16x32_f16(ah, bh[g], acc[mt][g], 0, 0, 0);
                acc[mt][g] = __builtin_amdgcn_mfma_f32_16x16x32_f16(ah, bl[g], acc[mt][g], 0, 0, 0);
                acc[mt][g] = __builtin_amdgcn_mfma_f32_16x16x32_f16(al, bh[g], acc[mt][g], 0, 0, 0);
            }
        }
    }

    // epilogue: lane owns all 4 gates for (m, j) -> fused cell update
    const int j = j0 + wn * 16 + l15;
    const float xbi = xb[0 * HDIM + j];
    const float xbf = xb[1 * HDIM + j];
    const float xbg = xb[2 * HDIM + j];
    const float xbo = xb[3 * HDIM + j];
    #pragma unroll
    for (int mt = 0; mt < 4; mt++) {
        #pragma unroll
        for (int reg = 0; reg < 4; reg++) {
            int m = m0 + wm * 64 + mt * 16 + quad * 4 + reg;
            float gi = acc[mt][0][reg] * SINV + xbi;
            float gf = acc[mt][1][reg] * SINV + xbf;
            float gg = acc[mt][2][reg] * SINV + xbg;
            float go = acc[mt][3][reg] * SINV + xbo;
            float si = 1.0f / (1.0f + expf(-gi));
            float sf = 1.0f / (1.0f + expf(-gf));
            float tg = tanhf(gg);
            float so = 1.0f / (1.0f + expf(-go));
            size_t idx = (size_t)m * HDIM + j;
            float cn = sf * c[idx] + si * tg;
            c[idx] = cn;
            float hv = so * tanhf(cn);
            float hs = hv * SH;
            f16 hh = (f16)hs;
            f16 hl = (f16)(hs - (float)hh);
            hhi_o[idx] = hh;
            hlo_o[idx] = hl;
        }
    }
}

// ---------------------------------------------------------------------------
// Per-step output: logits = h @ W_out^T + b_out (V=32), argmax/softmax,
// one-hot message, mask bookkeeping, per-block log-prob partial.
// h reconstructed from split pair: h = (hh + hl) / SH.
// ---------------------------------------------------------------------------
__global__ __launch_bounds__(256)
void out_step_kernel(const f16* __restrict__ hhi, const f16* __restrict__ hlo,
                     const float* __restrict__ W_out,
                     const float* __restrict__ b_out,
                     float* __restrict__ mask,
                     float* __restrict__ msg_t,
                     float* __restrict__ maskout_t,
                     float* __restrict__ lp_part,
                     const int* __restrict__ eos_ptr) {
    __shared__ __align__(16) float hs[8][128];
    __shared__ float ws[128][32];
    __shared__ float red[8];

    const int tid = threadIdx.x;
    const int v   = tid & 31;
    const int bb  = tid >> 5;          // 0..7
    const int b0  = blockIdx.x * 8;
    const int eos = *eos_ptr;

    float logit = 0.0f;
    for (int k0 = 0; k0 < HDIM; k0 += 128) {
        __syncthreads();
        {   // stage h: 8 rows x 128 k
            size_t base = (size_t)(b0 + bb) * HDIM + k0 + v * 4;
            f16x4 a = *(const f16x4*)(hhi + base);
            f16x4 b = *(const f16x4*)(hlo + base);
            #pragma unroll
            for (int i = 0; i < 4; i++)
                hs[bb][v * 4 + i] = ((float)a[i] + (float)b[i]) * HINV;
        }
        {   // stage W_out transposed
            int kk = bb * 16;
            const float* src = W_out + (size_t)v * HDIM + k0 + kk;
            float4 q0 = *(const float4*)(src + 0);
            float4 q1 = *(const float4*)(src + 4);
            float4 q2 = *(const float4*)(src + 8);
            float4 q3 = *(const float4*)(src + 12);
            ws[kk + 0][v] = q0.x;  ws[kk + 1][v] = q0.y;
            ws[kk + 2][v] = q0.z;  ws[kk + 3][v] = q0.w;
            ws[kk + 4][v] = q1.x;  ws[kk + 5][v] = q1.y;
            ws[kk + 6][v] = q1.z;  ws[kk + 7][v] = q1.w;
            ws[kk + 8][v] = q2.x;  ws[kk + 9][v] = q2.y;
            ws[kk + 10][v] = q2.z; ws[kk + 11][v] = q2.w;
            ws[kk + 12][v] = q3.x; ws[kk + 13][v] = q3.y;
            ws[kk + 14][v] = q3.z; ws[kk + 15][v] = q3.w;
        }
        __syncthreads();
        #pragma unroll
        for (int k = 0; k < 128; k++)
            logit = fmaf(hs[bb][k], ws[k][v], logit);
    }
    logit += b_out[v];

    // argmax over 32 lanes, first-index tie-break (np.argmax semantics)
    float mval = logit;
    int   midx = v;
    #pragma unroll
    for (int off = 16; off > 0; off >>= 1) {
        float ov = __shfl_xor(mval, off, 32);
        int   oi = __shfl_xor(midx, off, 32);
        if (ov > mval || (ov == mval && oi < midx)) { mval = ov; midx = oi; }
    }
    float s = expf(logit - mval);
    #pragma unroll
    for (int off = 16; off > 0; off >>= 1) s += __shfl_xor(s, off, 32);

    const int b = b0 + bb;
    msg_t[(size_t)b * VOCAB + v] = (v == midx) ? 1.0f : 0.0f;
    if (v == 0) {
        float mo = mask[b];
        maskout_t[b] = mo;
        red[bb] = mo * (-logf(s));    // log softmax at argmax = -log(sum)
        if (midx == eos) mask[b] = 0.0f;
    }
    __syncthreads();
    if (tid == 0) {
        float t = 0.0f;
        #pragma unroll
        for (int i = 0; i < 8; i++) t += red[i];
        lp_part[blockIdx.x] = t;
    }
}

__global__ void reduce_lp_kernel(const float* __restrict__ parts, int n,
                                 float* __restrict__ out) {
    __shared__ float sm[256];
    float s = 0.0f;
    for (int i = threadIdx.x; i < n; i += 256) s += parts[i];
    sm[threadIdx.x] = s;
    __syncthreads();
    for (int off = 128; off > 0; off >>= 1) {
        if (threadIdx.x < off) sm[threadIdx.x] += sm[threadIdx.x + off];
        __syncthreads();
    }
    if (threadIdx.x == 0) *out = sm[0];
}

// ---------------------------------------------------------------------------
extern "C" void kernel_launch(void* const* d_in, const int* in_sizes, int n_in,
                              void* d_out, int out_size, void* d_ws, size_t ws_size,
                              hipStream_t stream) {
    const float* enc_h  = (const float*)d_in[0];
    const float* enc_c  = (const float*)d_in[1];
    const float* W_ih   = (const float*)d_in[2];
    const float* b_ih   = (const float*)d_in[3];
    const float* W_hh   = (const float*)d_in[4];
    const float* b_hh   = (const float*)d_in[5];
    const float* W_out  = (const float*)d_in[6];
    const float* b_out  = (const float*)d_in[7];
    const float* x0     = (const float*)d_in[8];
    const int*   eosP   = (const int*)d_in[9];

    float* out     = (float*)d_out;
    float* msg     = out;                                   // [20,16384,32]
    float* maskout = out + (size_t)STEPS * BATCH * VOCAB;   // [20,1,16384]
    float* lp_out  = maskout + (size_t)STEPS * BATCH;       // scalar

    // workspace layout
    const size_t NH = (size_t)BATCH * HDIM;                 // 8388608
    char* w = (char*)d_ws;
    f16* hhi_a = (f16*)w;            w += NH * sizeof(f16);
    f16* hlo_a = (f16*)w;            w += NH * sizeof(f16);
    f16* hhi_b = (f16*)w;            w += NH * sizeof(f16);
    f16* hlo_b = (f16*)w;            w += NH * sizeof(f16);
    float* cbuf = (float*)w;         w += NH * sizeof(float);
    f16* Wsh = (f16*)w;              w += (size_t)G4 * HDIM * sizeof(f16);
    f16* Wsl = (f16*)w;              w += (size_t)G4 * HDIM * sizeof(f16);
    float* xb = (float*)w;           w += G4 * sizeof(float);
    float* maskbuf = (float*)w;      w += BATCH * sizeof(float);
    float* lp_parts = (float*)w;     // STEPS * (BATCH/8) floats

    hipMemcpyAsync(cbuf, enc_c, NH * sizeof(float), hipMemcpyDeviceToDevice, stream);
    init_mask_kernel<<<(BATCH + 255) / 256, 256, 0, stream>>>(maskbuf);
    init_xb_kernel<<<(G4 + 255) / 256, 256, 0, stream>>>(W_ih, b_ih, b_hh, x0, xb);
    split_kernel<<<((int)(G4 * HDIM) + 255) / 256, 256, 0, stream>>>(
        W_hh, SW, Wsh, Wsl, G4 * HDIM);
    split_kernel<<<((int)NH + 255) / 256, 256, 0, stream>>>(
        enc_h, SH, hhi_a, hlo_a, (int)NH);

    for (int t = 0; t < STEPS; t++) {
        const f16* hi_in = (t & 1) ? hhi_b : hhi_a;
        const f16* lo_in = (t & 1) ? hlo_b : hlo_a;
        f16* hi_out      = (t & 1) ? hhi_a : hhi_b;
        f16* lo_out      = (t & 1) ? hlo_a : hlo_b;
        gemm_cell_mfma<<<dim3(BATCH / 128, HDIM / 32), 256, 0, stream>>>(
            hi_in, lo_in, hi_out, lo_out, cbuf, Wsh, Wsl, xb);
        out_step_kernel<<<BATCH / 8, 256, 0, stream>>>(
            hi_out, lo_out, W_out, b_out, maskbuf,
            msg + (size_t)t * BATCH * VOCAB,
            maskout + (size_t)t * BATCH,
            lp_parts + (size_t)t * (BATCH / 8),
            eosP);
    }
    reduce_lp_kernel<<<1, 256, 0, stream>>>(lp_parts, STEPS * (BATCH / 8), lp_out);
}